// Round 6
// baseline (338.981 us; speedup 1.0000x reference)
//
#include <hip/hip_runtime.h>
#include <stdint.h>

#define BB 512
#define TT 1024
#define KK 48
#define PF 4

// mask may arrive as 1-byte bools (raw numpy) or as 4-byte words.
// mask[0][0..3] are guaranteed true (len >= T/2), so the first 32-bit word is
// 0x01010101 iff byte storage.
__device__ __forceinline__ int mask_at(const void* m, int idx, bool bytes) {
    return bytes ? (int)(((const uint8_t*)m)[idx] != 0)
                 : (int)(((const int*)m)[idx] != 0);
}

// wave-uniform broadcast from a fixed lane via v_readlane_b32 (SGPR result)
__device__ __forceinline__ float bcast(float v, int lane) {
    return __int_as_float(__builtin_amdgcn_readlane(__float_as_int(v), lane));
}

// ------------- forward algorithm + fused gold-path score -------------------
// One wave per batch row; lane j owns state j. Exp-domain recurrence
// p <- (E^T p) * exp(em_t), E = exp(trans) in 48 VGPRs.
// R2-R5 post-mortem: WRITE_SIZE ~45 MB/dispatch (semantic writes: 4 KB!)
// => the unrolled body was SPILLING to scratch every step; cause was peak
// live-range pressure (48 SGPR readlane results — SGPR_Count 96 of ~102 —
// plus 48 VGPR etr plus 16 pipe/eexp). Fix: broadcast in 4 groups of 12
// (<=12 SGPR results live; sched_barrier(0) stops the scheduler from
// re-hoisting them), no asm pins, PF=4.
// Renorm every 4th step: growth/step <= 48*e^{5.6} ~= 2^14 — f32-safe.
__global__ __launch_bounds__(64, 1) void crf_fwd(
    const float* __restrict__ em, const int* __restrict__ tags,
    const void* __restrict__ mask, const float* __restrict__ trans,
    const float* __restrict__ start, const float* __restrict__ endt,
    float* __restrict__ ws)
{
    const int b = blockIdx.x;
    const int lane = threadIdx.x;
    const bool active = lane < KK;
    const int j = active ? lane : KK - 1;   // clamp for safe loads

    const bool mb = (*(const int*)mask) == 0x01010101;

    // sequence length = popcount of prefix mask
    int cnt = 0;
    for (int t = lane; t < TT; t += 64) cnt += mask_at(mask, b * TT + t, mb);
    #pragma unroll
    for (int off = 32; off >= 1; off >>= 1) cnt += __shfl_xor(cnt, off);
    const int len = cnt;

    // E[i][j] = exp(trans[i][j]) for this lane's column j
    float etr[KK];
    #pragma unroll
    for (int i = 0; i < KK; ++i)
        etr[i] = active ? __expf(trans[i * KK + j]) : 0.0f;

    const float* emb = em + (size_t)b * TT * KK;

    // init: pcur = exp(S_0 - c), c = S_0[0]
    float s0i = start[j] + emb[j];
    float c = bcast(s0i, 0);
    float pcur = active ? __expf(s0i - c) : 0.0f;

    // emission prefetch pipeline keeps HBM/L2 latency off the serial chain
    float pipe[PF];
    #pragma unroll
    for (int d = 0; d < PF; ++d) pipe[d] = emb[(1 + d) * KK + j];

    // one forward step: pcur <- (E^T pcur) * e [ * 1/p0 if renorm ]
    auto step = [&](float e, bool renorm) {
        float scale = e;
        float q0, q1, q2, q3;
        float s[12];
        #pragma unroll
        for (int k = 0; k < 12; ++k) s[k] = bcast(pcur, k);
        __builtin_amdgcn_sched_barrier(0);
        if (renorm) {
            scale *= __builtin_amdgcn_rcpf(s[0]);
            c += __logf(s[0]);
        }
        q0 = s[0] * etr[0];
        q1 = s[1] * etr[1];
        q2 = s[2] * etr[2];
        q3 = s[3] * etr[3];
        #pragma unroll
        for (int k = 4; k < 12; k += 4) {
            q0 = fmaf(s[k],     etr[k],     q0);
            q1 = fmaf(s[k + 1], etr[k + 1], q1);
            q2 = fmaf(s[k + 2], etr[k + 2], q2);
            q3 = fmaf(s[k + 3], etr[k + 3], q3);
        }
        #pragma unroll
        for (int g = 1; g < 4; ++g) {
            #pragma unroll
            for (int k = 0; k < 12; ++k) s[k] = bcast(pcur, 12 * g + k);
            __builtin_amdgcn_sched_barrier(0);
            #pragma unroll
            for (int k = 0; k < 12; k += 4) {
                q0 = fmaf(s[k],     etr[12 * g + k],     q0);
                q1 = fmaf(s[k + 1], etr[12 * g + k + 1], q1);
                q2 = fmaf(s[k + 2], etr[12 * g + k + 2], q2);
                q3 = fmaf(s[k + 3], etr[12 * g + k + 3], q3);
            }
        }
        pcur = ((q0 + q1) + (q2 + q3)) * scale;
    };

    int t = 1;
    // ---- main loop: full PF-blocks, no per-substep guards ----
    while (t + PF <= len) {
        float eexp[PF];
        #pragma unroll
        for (int d = 0; d < PF; ++d) eexp[d] = __expf(pipe[d]);   // off-chain
        #pragma unroll
        for (int d = 0; d < PF; ++d) {
            int tt = t + PF + d; tt = tt < TT ? tt : TT - 1;
            pipe[d] = emb[tt * KK + j];
        }
        #pragma unroll
        for (int d = 0; d < PF; ++d) step(eexp[d], d == 0);
        t += PF;
    }
    // ---- tail: guarded, renorm every step (<= PF-1 steps) ----
    while (t < len) {
        float e = __expf(pipe[0]);
        #pragma unroll
        for (int d = 0; d < PF - 1; ++d) pipe[d] = pipe[d + 1];
        step(e, true);
        ++t;
    }

    // log_z = c + log(sum_j pcur_j * exp(end_j))
    float v = active ? pcur * __expf(endt[j]) : 0.0f;
    #pragma unroll
    for (int off = 32; off >= 1; off >>= 1) v += __shfl_xor(v, off);

    // ---- fused gold-path score (mask is prefix: m[t] == (t < len)) ----
    const int* tgb = tags + b * TT;
    float sq = 0.f;
    for (int tt2 = lane; tt2 < TT; tt2 += 64) {
        if (tt2 >= 1 && tt2 < len) {
            int tp = tgb[tt2 - 1], tc = tgb[tt2];
            sq += trans[tp * KK + tc] + emb[tt2 * KK + tc];
        }
    }
    #pragma unroll
    for (int off = 32; off >= 1; off >>= 1) sq += __shfl_xor(sq, off);

    if (lane == 0) {
        int t0 = tgb[0];
        ws[b]      = c + __logf(v);
        ws[BB + b] = sq + start[t0] + emb[t0] + endt[tgb[len - 1]];
    }
}

// ---------------- final mean reduction ----------------
__global__ __launch_bounds__(256) void crf_final(const float* __restrict__ ws,
                                                 float* __restrict__ out)
{
    __shared__ float red[256];
    float s = 0.f;
    for (int b = threadIdx.x; b < BB; b += 256) s += ws[b] - ws[BB + b];
    red[threadIdx.x] = s;
    __syncthreads();
    for (int off = 128; off > 0; off >>= 1) {
        if (threadIdx.x < off) red[threadIdx.x] += red[threadIdx.x + off];
        __syncthreads();
    }
    if (threadIdx.x == 0) out[0] = red[0] / (float)BB;
}

extern "C" void kernel_launch(void* const* d_in, const int* in_sizes, int n_in,
                              void* d_out, int out_size, void* d_ws, size_t ws_size,
                              hipStream_t stream) {
    const float* em    = (const float*)d_in[0];
    const int*   tags  = (const int*)d_in[1];
    const void*  mask  = d_in[2];
    const float* trans = (const float*)d_in[3];
    const float* start = (const float*)d_in[4];
    const float* endt  = (const float*)d_in[5];
    float* ws  = (float*)d_ws;
    float* out = (float*)d_out;

    crf_fwd  <<<BB, 64,  0, stream>>>(em, tags, mask, trans, start, endt, ws);
    crf_final<<<1,  256, 0, stream>>>(ws, out);
}